// Round 6
// baseline (2229.159 us; speedup 1.0000x reference)
//
#include <hip/hip_runtime.h>
#include <math.h>

#define Bn 32
#define Mn 2048
#define Nn 65536      // Bn * Mn
#define Hn 32768      // Nn / 2 (chunk for race-free c0)
#define SDn 16
#define CWn 512
#define EPSf 1e-5f
#define KGF 8
#define WTOT 573440   // logical weight elements
#define LSC 2048.0f   // lo-plane scale (2^11)
#define LSCI (1.0f / 2048.0f)

typedef unsigned short u16;
typedef _Float16 fp16_t;
typedef __attribute__((ext_vector_type(8))) _Float16 h8v;  // MFMA A/B frag: 8 f16
typedef __attribute__((ext_vector_type(4))) float f4v;     // MFMA C/D frag: 4 fp32

__device__ __forceinline__ u16 f2h(float f) {
    union { fp16_t h; u16 u; } c; c.h = (fp16_t)f; return c.u;
}
__device__ __forceinline__ float h2f(u16 u) {
    union { fp16_t h; u16 u; } c; c.u = u; return (float)c.h;
}
__device__ __forceinline__ void fsplit(float f, u16& hi, u16& lo) {
    hi = f2h(f);
    lo = f2h((f - h2f(hi)) * LSC);
}
__device__ __forceinline__ float fjoin(u16 hi, u16 lo) {
    return h2f(hi) + h2f(lo) * LSCI;
}
// async global->LDS, 16 bytes/lane (dest must be wave-uniform base + lane*16)
__device__ __forceinline__ void gll16(const u16* g, u16* l) {
    __builtin_amdgcn_global_load_lds((const __attribute__((address_space(1))) void*)g,
                                     (__attribute__((address_space(3))) void*)l, 16, 0, 0);
}
__device__ __forceinline__ unsigned umin(unsigned a, unsigned b) { return a < b ? a : b; }
__device__ __forceinline__ unsigned umax(unsigned a, unsigned b) { return a > b ? a : b; }

// ============================================================================
// prep: weights fp32 -> split layout, normalize s -> xs, zero stats (fused)
// ============================================================================
__global__ __launch_bounds__(256) void prep_kernel(
    const float* __restrict__ wm1, const float* __restrict__ wm2,
    const float* __restrict__ wc0, const float* __restrict__ wc1,
    const float* __restrict__ wc2, const float* __restrict__ wc3,
    const float* __restrict__ s,
    u16* __restrict__ wbuf, u16* __restrict__ xs, float* __restrict__ stats)
{
    const int bid = blockIdx.x;
    const int tid = threadIdx.x;
    if (bid < 2240) {
        // ---- weight conversion: [Cout][hi[Cin] | lo[Cin]] ----
        int i = bid * 256 + tid;
        float w; int r, k, Cin; size_t base;
        if (i < 8192) {                              // m1 padded [256][32]
            r = i >> 5; k = i & 31; Cin = 32; base = 0;
            w = (k < SDn) ? wm1[r * SDn + k] : 0.f;
        } else {
            int j = i - 8192;
            if (j < 131072)                    { r = j >> 8; k = j & 255; Cin = 256; base = 16384;   w = wm2[j]; }
            else if ((j -= 131072) < 262144)   { r = j >> 9; k = j & 511; Cin = 512; base = 278528;  w = wc0[j]; }
            else if ((j -= 262144) < 131072)   { r = j >> 9; k = j & 511; Cin = 512; base = 802816;  w = wc1[j]; }
            else if ((j -= 131072) < 32768)    { r = j >> 8; k = j & 255; Cin = 256; base = 1064960; w = wc2[j]; }
            else { j -= 32768;                   r = j >> 7; k = j & 127; Cin = 128; base = 1130496; w = wc3[j]; }
        }
        const size_t addr = base + (size_t)r * (2 * Cin) + k;
        u16 hi, lo; fsplit(w, hi, lo);
        wbuf[addr] = hi;
        wbuf[addr + Cin] = lo;
    } else if (bid < 2496) {
        // ---- normalize s[B,16,M] -> xs[N][64] (hi[32]|lo[32], upper 16 zero)
        const int b2 = bid - 2240;
        const int m = (b2 & 7) * 256 + tid;
        const int b = b2 >> 3;
        const float* sp = s + (size_t)b * SDn * Mn + m;
        float v[SDn]; float sq = 0.f;
#pragma unroll
        for (int c = 0; c < SDn; ++c) { v[c] = sp[(size_t)c * Mn]; sq += v[c] * v[c]; }
        const float r = 1.0f / sqrtf(sq);
        unsigned int uh[8], ul[8];
#pragma unroll
        for (int c = 0; c < 8; ++c) {
            u16 h0, l0, h1, l1;
            fsplit(v[2 * c] * r, h0, l0);
            fsplit(v[2 * c + 1] * r, h1, l1);
            uh[c] = (unsigned int)h0 | ((unsigned int)h1 << 16);
            ul[c] = (unsigned int)l0 | ((unsigned int)l1 << 16);
        }
        uint4* xp = (uint4*)(xs + (size_t)(b * Mn + m) * 64);
        xp[0] = make_uint4(uh[0], uh[1], uh[2], uh[3]);
        xp[1] = make_uint4(uh[4], uh[5], uh[6], uh[7]);
        xp[2] = make_uint4(0, 0, 0, 0);
        xp[3] = make_uint4(0, 0, 0, 0);
        xp[4] = make_uint4(ul[0], ul[1], ul[2], ul[3]);
        xp[5] = make_uint4(ul[4], ul[5], ul[6], ul[7]);
        xp[6] = make_uint4(0, 0, 0, 0);
        xp[7] = make_uint4(0, 0, 0, 0);
    } else {
        // ---- zero BN stats (4096 floats) ----
        float4 z4 = {0.f, 0.f, 0.f, 0.f};
        float4* sp4 = (float4*)stats;
#pragma unroll
        for (int k = 0; k < 4; ++k) sp4[tid * 4 + k] = z4;
    }
}

// ---- split fp16 MFMA GEMM, full double-buffered pipeline -------------------
// acc0 = Wh*Xh ; accL = Wh*Xl' + Wl'*Xh ; result = acc0 + accL/2048
// Geometry generalized by NT (threads/block): wave grid RW x CWv covering
// BM=RW*64 x BN=CWv*64 tile, per-wave sub-tile always 64x64 (4x4 frags).
// Both A and B tiles double-buffered; stage(ks+2) issued after compute(ks),
// per-step wait is COUNTED vmcnt(VMSTEP); never vmcnt(0) mid-loop.
// MFMA block is 3 independent passes (no adjacent dependent MFMAs);
// per-accumulator op order unchanged -> bit-identical.
// IBN=1: BN finalize fused (stats+g+be -> scale/shift in LDS prologue).
template<int RW, int CWv, int EPI, int MY, int IBN, int CINT, int NT>
__global__ __launch_bounds__(NT) void mfma_gemm(
    const u16* __restrict__ W, const u16* __restrict__ X, u16* __restrict__ Y,
    const float* __restrict__ bias, const float* __restrict__ zmod,
    const float* __restrict__ statsIn, const float* __restrict__ gin,
    const float* __restrict__ bein, float* __restrict__ stats, int Cout)
{
    constexpr int BM = RW * 64, BN = CWv * 64;
    constexpr int ASEG = (BM * 4) / NT;         // A staging iters (4 loads/row)
    constexpr int BSEG = (BN * 4) / NT;         // B staging iters
    constexpr int LMY = (MY == 1) ? 0 : (MY == 2) ? 1 : (MY == 4) ? 2 : 3;
    constexpr int SW = 2 * CINT;
    constexpr int NST = CINT >> 5;              // K-steps
    constexpr int VMSTEP = 2 * ASEG + 2 * BSEG; // gll16 per thread per step
    constexpr int SSTATN = (EPI == 2) ? (CWv * BM * 2) : 1;
    constexpr int BNN = IBN ? (CINT * 2) : 1;
    constexpr int AUXN = (SSTATN > BNN) ? SSTATN : BNN;
    __shared__ __align__(16) u16 Ah[2][BM * 32], Al[2][BM * 32];
    __shared__ __align__(16) u16 Bh[2][BN * 32], Bl[2][BN * 32];
    __shared__ float saux[AUXN];            // main loop: BN params; epilogue: stats

    const int tid = threadIdx.x;
    const int wave = tid >> 6;
    const int lane = tid & 63;
    const int wm = wave & (RW - 1), wn = wave / RW;
    const int l15 = lane & 15, q = lane >> 4;
    const int lin = blockIdx.x;
    const int xcd = lin & 7;
    const int jj = lin >> 3;
    const int m0 = (jj & (MY - 1)) * BM;
    const int n0 = (xcd + ((jj >> LMY) << 3)) * BN;

    f4v acc0[4][4], accL[4][4];
#pragma unroll
    for (int i = 0; i < 4; ++i)
#pragma unroll
        for (int j = 0; j < 4; ++j) {
            acc0[i][j] = (f4v){0.f, 0.f, 0.f, 0.f};
            accL[i][j] = (f4v){0.f, 0.f, 0.f, 0.f};
        }

    // ---- staging: one full K-step (A + B, both planes) into buffer `buf` ----
    auto stageAB = [&](int ks, int buf) {
        const int k0 = ks << 5;
#pragma unroll
        for (int s = 0; s < ASEG; ++s) {
            const int flat = s * NT + tid;
            const int row = flat >> 2;
            const int qs = (flat & 3) ^ ((row >> 1) & 3);   // swizzled source chunk
            const u16* ga = W + (size_t)(m0 + row) * SW + k0 + qs * 8;
            gll16(ga, Ah[buf] + flat * 8);
            gll16(ga + CINT, Al[buf] + flat * 8);
        }
#pragma unroll
        for (int s = 0; s < BSEG; ++s) {
            const int flat = s * NT + tid;
            const int row = flat >> 2;
            const int qs = (flat & 3) ^ ((row >> 1) & 3);
            const u16* gb = X + (size_t)(n0 + row) * SW + k0 + qs * 8;
            gll16(gb, Bh[buf] + flat * 8);
            gll16(gb + CINT, Bl[buf] + flat * 8);
        }
    };

    if constexpr (IBN) {
        // fused BN finalize: raw (sum,sumsq) + g + be -> (scale, shift) in LDS
        const float inv = 1.0f / (float)Nn;
        for (int c = tid; c < CINT; c += NT) {
            const float mean = statsIn[c * 2] * inv;
            const float var = statsIn[c * 2 + 1] * inv - mean * mean;
            const float sc = gin[c] / sqrtf(var + EPSf);
            saux[c * 2] = sc;
            saux[c * 2 + 1] = fmaf(-mean, sc, bein[c]);
        }
        asm volatile("s_waitcnt vmcnt(0) lgkmcnt(0)" ::: "memory");
    }
    stageAB(0, 0);                           // prologue: two steps in flight
    if constexpr (NST > 1) stageAB(1, 1);

#pragma unroll 1
    for (int ks = 0; ks < NST; ++ks) {
        const int cur = ks & 1;
        if (ks + 1 < NST) {
            // step ks landed; step ks+1 stays in flight across this compute
            asm volatile("s_waitcnt vmcnt(%0)" :: "n"(VMSTEP) : "memory");
        } else {
            asm volatile("s_waitcnt vmcnt(0)" ::: "memory");
        }
        __builtin_amdgcn_s_barrier();        // all waves' cur-tile loads landed
        __builtin_amdgcn_sched_barrier(0);
        h8v afh[4], afl[4], bfh[4], bfl[4];
#pragma unroll
        for (int i = 0; i < 4; ++i) {
            const int ar = wm * 64 + i * 16 + l15;
            const int ao = ar * 32 + ((q ^ ((ar >> 1) & 3)) << 3);
            afh[i] = *(const h8v*)(Ah[cur] + ao);
            afl[i] = *(const h8v*)(Al[cur] + ao);
        }
#pragma unroll
        for (int j = 0; j < 4; ++j) {
            const int br = wn * 64 + j * 16 + l15;
            const int bo = br * 32 + ((q ^ ((br >> 1) & 3)) << 3);
            bfh[j] = *(const h8v*)(Bh[cur] + bo);
            bfl[j] = *(const h8v*)(Bl[cur] + bo);
        }
        if constexpr (IBN) {
            // frag elems are LOGICAL channels k0 + q*8 + e; params from LDS
            const int kb = ((ks << 5) + q * 8) * 2;
            const float4 p0 = *(const float4*)(saux + kb);
            const float4 p1 = *(const float4*)(saux + kb + 4);
            const float4 p2 = *(const float4*)(saux + kb + 8);
            const float4 p3 = *(const float4*)(saux + kb + 12);
            const float sc8[8] = {p0.x, p0.z, p1.x, p1.z, p2.x, p2.z, p3.x, p3.z};
            const float sh8[8] = {p0.y, p0.w, p1.y, p1.w, p2.y, p2.w, p3.y, p3.w};
#pragma unroll
            for (int j = 0; j < 4; ++j) {
#pragma unroll
                for (int e = 0; e < 8; ++e) {
                    const float v = (float)bfh[j][e] + (float)bfl[j][e] * LSCI;
                    const float a = fmaxf(fmaf(v, sc8[e], sh8[e]), 0.f);
                    const fp16_t hh = (fp16_t)a;
                    bfh[j][e] = hh;
                    bfl[j][e] = (fp16_t)((a - (float)hh) * LSC);
                }
            }
        }
        __builtin_amdgcn_s_setprio(1);
        // 3 independent passes: no adjacent dependent MFMAs (16 ops apart);
        // per-accumulator order preserved (accL: term1 then term2).
#pragma unroll
        for (int i = 0; i < 4; ++i)
#pragma unroll
            for (int j = 0; j < 4; ++j)
                accL[i][j] = __builtin_amdgcn_mfma_f32_16x16x32_f16(afh[i], bfl[j], accL[i][j], 0, 0, 0);
#pragma unroll
        for (int i = 0; i < 4; ++i)
#pragma unroll
            for (int j = 0; j < 4; ++j)
                acc0[i][j] = __builtin_amdgcn_mfma_f32_16x16x32_f16(afh[i], bfh[j], acc0[i][j], 0, 0, 0);
#pragma unroll
        for (int i = 0; i < 4; ++i)
#pragma unroll
            for (int j = 0; j < 4; ++j)
                accL[i][j] = __builtin_amdgcn_mfma_f32_16x16x32_f16(afl[i], bfh[j], accL[i][j], 0, 0, 0);
        __builtin_amdgcn_s_setprio(0);
        __builtin_amdgcn_s_barrier();        // frag reads retired -> overwrite safe
        if (ks + 2 < NST) stageAB(ks + 2, cur);
    }

    // ---- epilogue ----
    float* sstat = saux;
    const int bb = n0 >> 11;
    const int SY = 2 * Cout;
#pragma unroll
    for (int i = 0; i < 4; ++i) {
        const int chb = m0 + wm * 64 + i * 16 + q * 4;
        const float4 bias4 = *(const float4*)(bias + chb);
        float z0 = 0.f, z1 = 0.f, z2 = 0.f, z3 = 0.f;
        if constexpr (EPI == 1) {
            const float4 z4 = *(const float4*)(zmod + bb * CWn + chb);
            z0 = z4.x; z1 = z4.y; z2 = z4.z; z3 = z4.w;
        }
        float ssum[4] = {0.f, 0.f, 0.f, 0.f}, ssq[4] = {0.f, 0.f, 0.f, 0.f};
#pragma unroll
        for (int j = 0; j < 4; ++j) {
            const int n = n0 + wn * 64 + j * 16 + l15;
            float v0 = fmaf(accL[i][j][0], LSCI, acc0[i][j][0]) + bias4.x;
            float v1 = fmaf(accL[i][j][1], LSCI, acc0[i][j][1]) + bias4.y;
            float v2 = fmaf(accL[i][j][2], LSCI, acc0[i][j][2]) + bias4.z;
            float v3 = fmaf(accL[i][j][3], LSCI, acc0[i][j][3]) + bias4.w;
            if constexpr (EPI == 0) {
                v0 = fmaxf(v0, 0.f); v1 = fmaxf(v1, 0.f); v2 = fmaxf(v2, 0.f); v3 = fmaxf(v3, 0.f);
            } else if constexpr (EPI == 1) {
                v0 = fminf(fmaxf(v0, -1.f), 1.f) * z0;
                v1 = fminf(fmaxf(v1, -1.f), 1.f) * z1;
                v2 = fminf(fmaxf(v2, -1.f), 1.f) * z2;
                v3 = fminf(fmaxf(v3, -1.f), 1.f) * z3;
            } else {
                ssum[0] += v0; ssum[1] += v1; ssum[2] += v2; ssum[3] += v3;
                ssq[0] += v0 * v0; ssq[1] += v1 * v1; ssq[2] += v2 * v2; ssq[3] += v3 * v3;
            }
            u16 h0, l0, h1, l1, h2, l2, h3, l3;
            fsplit(v0, h0, l0); fsplit(v1, h1, l1);
            fsplit(v2, h2, l2); fsplit(v3, h3, l3);
            ushort4 hv = {h0, h1, h2, h3};
            ushort4 lv = {l0, l1, l2, l3};
            u16* yp = Y + (size_t)n * SY + chb;
            *(ushort4*)yp = hv;
            *(ushort4*)(yp + Cout) = lv;
        }
        if constexpr (EPI == 2) {
#pragma unroll
            for (int r = 0; r < 4; ++r) {
#pragma unroll
                for (int d = 1; d < 16; d <<= 1) {
                    ssum[r] += __shfl_xor(ssum[r], d);
                    ssq[r]  += __shfl_xor(ssq[r], d);
                }
            }
            if (l15 == 0) {
                const int chl = wm * 64 + i * 16 + q * 4;
#pragma unroll
                for (int r = 0; r < 4; ++r) {
                    sstat[(wn * BM + chl + r) * 2]     = ssum[r];
                    sstat[(wn * BM + chl + r) * 2 + 1] = ssq[r];
                }
            }
        }
    }
    if constexpr (EPI == 2) {
        __syncthreads();
        if (tid < BM) {
            float s0 = 0.f, s1 = 0.f;
#pragma unroll
            for (int w = 0; w < CWv; ++w) {
                s0 += sstat[(w * BM + tid) * 2];
                s1 += sstat[(w * BM + tid) * 2 + 1];
            }
            atomicAdd(&stats[(m0 + tid) * 2], s0);
            atomicAdd(&stats[(m0 + tid) * 2 + 1], s1);
        }
    }
}

// ---- final 64->3 conv (fused BN finalize + BN+ReLU on split input) ---------
__global__ __launch_bounds__(256) void finalconv_pm(
    const u16* __restrict__ y3, const float* __restrict__ statsIn,
    const float* __restrict__ gin, const float* __restrict__ bein,
    const float* __restrict__ wout, const float* __restrict__ bout,
    float* __restrict__ pts)
{
    __shared__ float swo[3][64];
    __shared__ float ssc[64], ssh[64];
    const int tid = threadIdx.x;
    if (tid < 192) swo[tid / 64][tid % 64] = wout[tid];
    if (tid < 64) {
        // fused c3 BN finalize (identical op order to old finalize_kernel)
        const float inv = 1.0f / (float)Nn;
        const float mean = statsIn[tid * 2] * inv;
        const float var = statsIn[tid * 2 + 1] * inv - mean * mean;
        const float sc = gin[tid] / sqrtf(var + EPSf);
        ssc[tid] = sc;
        ssh[tid] = fmaf(-mean, sc, bein[tid]);
    }
    __syncthreads();
    const int n = blockIdx.x * 256 + tid;
    const uint4* yph = (const uint4*)(y3 + (size_t)n * 128);
    float d0 = bout[0], d1 = bout[1], d2 = bout[2];
#pragma unroll
    for (int cc = 0; cc < 8; ++cc) {
        const uint4 H = yph[cc];
        const uint4 L = yph[8 + cc];
        const unsigned hu[4] = {H.x, H.y, H.z, H.w};
        const unsigned lu[4] = {L.x, L.y, L.z, L.w};
#pragma unroll
        for (int e = 0; e < 4; ++e) {
            const int c = cc * 8 + e * 2;
            const float v0 = fjoin((u16)(hu[e] & 0xffff), (u16)(lu[e] & 0xffff));
            const float v1 = fjoin((u16)(hu[e] >> 16), (u16)(lu[e] >> 16));
            const float a0 = fmaxf(fmaf(v0, ssc[c], ssh[c]), 0.f);
            const float a1 = fmaxf(fmaf(v1, ssc[c + 1], ssh[c + 1]), 0.f);
            d0 = fmaf(a0, swo[0][c], d0); d0 = fmaf(a1, swo[0][c + 1], d0);
            d1 = fmaf(a0, swo[1][c], d1); d1 = fmaf(a1, swo[1][c + 1], d1);
            d2 = fmaf(a0, swo[2][c], d2); d2 = fmaf(a1, swo[2][c + 1], d2);
        }
    }
    float4 p = {d0, d1, d2, d0 * d0 + d1 * d1 + d2 * d2};
    *(float4*)(pts + (size_t)n * 4) = p;
}

// ---- graph filtering: 16 threads/point, packed u32 keys --------------------
__global__ __launch_bounds__(512) void knn_kernel(const float* __restrict__ pts,
                                                  float* __restrict__ out) {
    __shared__ __align__(16) float4 sp[Mn];   // 32 KB -> 4 blocks/CU (wave cap)
    const int b = blockIdx.y;
    const int tid = threadIdx.x;
    const float4* pb = (const float4*)pts + (size_t)b * Mn;
    for (int i = tid; i < Mn; i += 512) sp[i] = pb[i];
    __syncthreads();
    const int lane = tid & 63;
    const int wv = tid >> 6;                    // 0..7
    const int seg = lane & 15;                  // segment 0..15 (128 cands each)
    const int ptl = (wv << 2) | (lane >> 4);    // point-local 0..31
    const int m = blockIdx.x * 32 + ptl;
    const float4 p = sp[m];
    // self-exclusion: only the owning segment can ever match (tt <= 127 < 128)
    const int cself = (seg == (m >> 7)) ? (m & 127) : 128;
    const int nb = seg << 7;
    unsigned bk[8];
#pragma unroll
    for (int k = 0; k < 8; ++k) bk[k] = 0xFFFFFFFFu;
    for (int t = 0; t < 128; ++t) {
        const int tt = (t + seg) & 127;         // stagger start by seg (bank tiling)
        const float4 q = sp[nb | tt];
        const float dot = fmaf(p.x, q.x, fmaf(p.y, q.y, p.z * q.z));
        float d = fmaf(-2.f, dot, q.w + p.w);   // true squared distance (+-ulp)
        d = fmaxf(d, 0.f);                      // keep uint-monotone (sign bit off)
        unsigned key = (__float_as_uint(d) & 0xFFFFFF80u) | (unsigned)tt;
        key = (tt == cself) ? 0xFFFFFFFFu : key;
        // branchless sorted insert, min/max only
        bk[7] = umin(bk[7], key);
#pragma unroll
        for (int k = 6; k >= 0; --k) {
            const unsigned lo = umin(bk[k], bk[k + 1]);
            bk[k + 1] = umax(bk[k], bk[k + 1]);
            bk[k] = lo;
        }
    }
    // keep originals for index recovery after the merge
    unsigned ok[8];
#pragma unroll
    for (int k = 0; k < 8; ++k) ok[k] = bk[k];
    // 4 bitonic merge rounds across the 16-lane group (partner = lane ^ r)
#pragma unroll
    for (int r = 1; r <= 8; r <<= 1) {
        unsigned od[8], md[8];
#pragma unroll
        for (int k = 0; k < 8; ++k) od[k] = (unsigned)__shfl_xor((int)bk[k], r);
#pragma unroll
        for (int k = 0; k < 8; ++k) md[k] = umin(bk[k], od[7 - k]);  // lowest-8 of union
#define CSU(a, c) { const unsigned lo_ = umin(md[a], md[c]); md[c] = umax(md[a], md[c]); md[a] = lo_; }
        CSU(0,4); CSU(1,5); CSU(2,6); CSU(3,7);
        CSU(0,2); CSU(1,3); CSU(4,6); CSU(5,7);
        CSU(0,1); CSU(2,3); CSU(4,5); CSU(6,7);
#undef CSU
#pragma unroll
        for (int k = 0; k < 8; ++k) bk[k] = md[k];
    }
    const unsigned TK = bk[7];                  // global 8th-smallest key
    // recovery: scan own 8 survivors vs TK; strict-less + equal-blend
    float slt[4] = {0.f, 0.f, 0.f, 0.f};        // x, y, z, count (key < TK)
    float seq[4] = {0.f, 0.f, 0.f, 0.f};        // x, y, z, count (key == TK)
#pragma unroll
    for (int k = 0; k < 8; ++k) {
        const unsigned key = ok[k];
        const float4 q = sp[nb | (int)(key & 127u)];
        const bool lt = key < TK;
        const bool eq = key == TK;
        slt[0] += lt ? q.x : 0.f; slt[1] += lt ? q.y : 0.f;
        slt[2] += lt ? q.z : 0.f; slt[3] += lt ? 1.f : 0.f;
        seq[0] += eq ? q.x : 0.f; seq[1] += eq ? q.y : 0.f;
        seq[2] += eq ? q.z : 0.f; seq[3] += eq ? 1.f : 0.f;
    }
#pragma unroll
    for (int r = 1; r <= 8; r <<= 1) {
#pragma unroll
        for (int k = 0; k < 4; ++k) {
            slt[k] += __shfl_xor(slt[k], r);
            seq[k] += __shfl_xor(seq[k], r);
        }
    }
    if (seg == 0) {
        const float scale = (8.f - slt[3]) / seq[3];   // seq[3] >= 1 guaranteed
        const float nx = fmaf(scale, seq[0], slt[0]);
        const float ny = fmaf(scale, seq[1], slt[1]);
        const float nz = fmaf(scale, seq[2], slt[2]);
        const float s8 = 0.125f;
        float* ob = out + (size_t)b * 3 * Mn;
        ob[m]          = 2.f * p.x - nx * s8;
        ob[Mn + m]     = 2.f * p.y - ny * s8;
        ob[2 * Mn + m] = 2.f * p.z - nz * s8;
    }
}

// ============================================================================
extern "C" void kernel_launch(void* const* d_in, const int* in_sizes, int n_in,
                              void* d_out, int out_size, void* d_ws, size_t ws_size,
                              hipStream_t stream)
{
    (void)in_sizes; (void)n_in; (void)out_size;
    const float* z     = (const float*)d_in[0];
    const float* s     = (const float*)d_in[1];
    const float* w_m1  = (const float*)d_in[2];
    const float* b_m1  = (const float*)d_in[3];
    const float* w_m2  = (const float*)d_in[4];
    const float* b_m2  = (const float*)d_in[5];
    const float* w_out = (const float*)d_in[6];
    const float* b_out = (const float*)d_in[7];
    const float* w_c[4]  = {(const float*)d_in[8],  (const float*)d_in[12], (const float*)d_in[16], (const float*)d_in[20]};
    const float* b_c[4]  = {(const float*)d_in[9],  (const float*)d_in[13], (const float*)d_in[17], (const float*)d_in[21]};
    const float* g_c[4]  = {(const float*)d_in[10], (const float*)d_in[14], (const float*)d_in[18], (const float*)d_in[22]};
    const float* be_c[4] = {(const float*)d_in[11], (const float*)d_in[15], (const float*)d_in[19], (const float*)d_in[23]};

    char* ws = (char*)d_ws;
    const size_t MB = 1024ull * 1024ull;
    float* outp = (float*)d_out;
    if (ws_size < 208 * MB) return;   // proven: harness provides >= 208 MiB

    // -------- split-fp16 MFMA path (peak 204 MiB) --------
    u16*   wbuf  = (u16*)ws;
    float* stats = (float*)(ws + 3 * MB);
    u16*   xs  = (u16*)(ws + 4 * MB);
    u16*   x1  = (u16*)(ws + 12 * MB);
    u16*   x2  = (u16*)(ws + 76 * MB);
    u16*   y0  = (u16*)(ws + 12 * MB);   // contiguous after both chunks (RAW)
    u16*   y0a = (u16*)(ws + 12 * MB);   // rows [0, 32K)
    u16*   y0b = (u16*)(ws + 76 * MB);   // rows [32K, 64K)
    u16*   y1  = (u16*)(ws + 140 * MB);  // RAW c1 output
    u16*   y2  = (u16*)(ws + 12 * MB);   // RAW c2 output
    u16*   y3  = (u16*)(ws + 76 * MB);   // RAW c3 output
    float* pts = (float*)(ws + 4 * MB);

    prep_kernel<<<2497, 256, 0, stream>>>(w_m1, w_m2, w_c[0], w_c[1], w_c[2], w_c[3], s, wbuf, xs, stats);
    // m1: [N][32] -> [N][256]  (128x128 tile, 256 thr; Ntiles=512, MY=2 -> 1024 blocks)
    mfma_gemm<2, 2, 0, 2, 0, 32, 256><<<1024, 256, 0, stream>>>(wbuf, xs, x1, b_m1, nullptr, nullptr, nullptr, nullptr, nullptr, 256);
    // m2: [N][256] -> [N][512] (256x256 tile, 1024 thr; Ntiles=256, MY=2 -> 512 blocks)
    mfma_gemm<4, 4, 1, 2, 0, 256, 1024><<<512, 1024, 0, stream>>>(wbuf + 16384, x1, x2, b_m2, z, nullptr, nullptr, nullptr, nullptr, 512);
    // c0 a/b: rows halves (256x256 tile; Ntiles=128, MY=2 -> 256 blocks each) -> RAW y0 + stats
    // (NOT mergeable: y0b overwrites x2 rows [0,32K) which c0a reads -> must stay sequential)
    mfma_gemm<4, 4, 2, 2, 0, 512, 1024><<<256, 1024, 0, stream>>>(wbuf + 278528, x2, y0a, b_c[0], nullptr, nullptr, nullptr, nullptr, stats + 0, 512);
    mfma_gemm<4, 4, 2, 2, 0, 512, 1024><<<256, 1024, 0, stream>>>(wbuf + 278528, x2 + (size_t)Hn * 1024, y0b, b_c[0], nullptr, nullptr, nullptr, nullptr, stats + 0, 512);
    // c1: BN0 finalize fused from stats+0 (256x256 tile, MY=1 -> 256 blocks); RAW y1 + stats
    mfma_gemm<4, 4, 2, 1, 1, 512, 1024><<<256, 1024, 0, stream>>>(wbuf + 802816, y0, y1, b_c[1], nullptr, stats + 0, g_c[0], be_c[0], stats + 1024, 256);
    // c2: BN1 finalize fused from stats+1024 (128x256 tile, 512 thr, MY=1 -> 256 blocks); RAW y2 + stats
    mfma_gemm<2, 4, 2, 1, 1, 256, 512><<<256, 512, 0, stream>>>(wbuf + 1064960, y1, y2, b_c[2], nullptr, stats + 1024, g_c[1], be_c[1], stats + 2048, 128);
    // c3: BN2 finalize fused from stats+2048 (64x256, 256 thr); RAW y3 + stats
    mfma_gemm<1, 4, 2, 1, 1, 128, 256><<<256, 256, 0, stream>>>(wbuf + 1130496, y2, y3, b_c[3], nullptr, stats + 2048, g_c[2], be_c[2], stats + 3072, 64);
    // finalconv: BN3 finalize fused from stats+3072
    finalconv_pm<<<Nn / 256, 256, 0, stream>>>(y3, stats + 3072, g_c[3], be_c[3], w_out, b_out, pts);
    knn_kernel<<<dim3(Mn / 32, Bn), 512, 0, stream>>>(pts, outp);
}

// Round 8
// 631.792 us; speedup vs baseline: 3.5283x; 3.5283x over previous
//
#include <hip/hip_runtime.h>
#include <math.h>

#define Bn 32
#define Mn 2048
#define Nn 65536      // Bn * Mn
#define Hn 32768      // Nn / 2 (chunk for race-free c0)
#define SDn 16
#define CWn 512
#define EPSf 1e-5f
#define KGF 8
#define WTOT 573440   // logical weight elements
#define LSC 2048.0f   // lo-plane scale (2^11)
#define LSCI (1.0f / 2048.0f)

typedef unsigned short u16;
typedef _Float16 fp16_t;
typedef __attribute__((ext_vector_type(8))) _Float16 h8v;  // MFMA A/B frag: 8 f16
typedef __attribute__((ext_vector_type(4))) float f4v;     // MFMA C/D frag: 4 fp32

__device__ __forceinline__ u16 f2h(float f) {
    union { fp16_t h; u16 u; } c; c.h = (fp16_t)f; return c.u;
}
__device__ __forceinline__ float h2f(u16 u) {
    union { fp16_t h; u16 u; } c; c.u = u; return (float)c.h;
}
__device__ __forceinline__ void fsplit(float f, u16& hi, u16& lo) {
    hi = f2h(f);
    lo = f2h((f - h2f(hi)) * LSC);
}
__device__ __forceinline__ float fjoin(u16 hi, u16 lo) {
    return h2f(hi) + h2f(lo) * LSCI;
}
// async global->LDS, 16 bytes/lane (dest must be wave-uniform base + lane*16)
__device__ __forceinline__ void gll16(const u16* g, u16* l) {
    __builtin_amdgcn_global_load_lds((const __attribute__((address_space(1))) void*)g,
                                     (__attribute__((address_space(3))) void*)l, 16, 0, 0);
}
__device__ __forceinline__ unsigned umin(unsigned a, unsigned b) { return a < b ? a : b; }
__device__ __forceinline__ unsigned umax(unsigned a, unsigned b) { return a > b ? a : b; }

// ============================================================================
// prep: weights fp32 -> split layout, normalize s -> xs, zero stats (fused)
// ============================================================================
__global__ __launch_bounds__(256) void prep_kernel(
    const float* __restrict__ wm1, const float* __restrict__ wm2,
    const float* __restrict__ wc0, const float* __restrict__ wc1,
    const float* __restrict__ wc2, const float* __restrict__ wc3,
    const float* __restrict__ s,
    u16* __restrict__ wbuf, u16* __restrict__ xs, float* __restrict__ stats)
{
    const int bid = blockIdx.x;
    const int tid = threadIdx.x;
    if (bid < 2240) {
        // ---- weight conversion: [Cout][hi[Cin] | lo[Cin]] ----
        int i = bid * 256 + tid;
        float w; int r, k, Cin; size_t base;
        if (i < 8192) {                              // m1 padded [256][32]
            r = i >> 5; k = i & 31; Cin = 32; base = 0;
            w = (k < SDn) ? wm1[r * SDn + k] : 0.f;
        } else {
            int j = i - 8192;
            if (j < 131072)                    { r = j >> 8; k = j & 255; Cin = 256; base = 16384;   w = wm2[j]; }
            else if ((j -= 131072) < 262144)   { r = j >> 9; k = j & 511; Cin = 512; base = 278528;  w = wc0[j]; }
            else if ((j -= 262144) < 131072)   { r = j >> 9; k = j & 511; Cin = 512; base = 802816;  w = wc1[j]; }
            else if ((j -= 131072) < 32768)    { r = j >> 8; k = j & 255; Cin = 256; base = 1064960; w = wc2[j]; }
            else { j -= 32768;                   r = j >> 7; k = j & 127; Cin = 128; base = 1130496; w = wc3[j]; }
        }
        const size_t addr = base + (size_t)r * (2 * Cin) + k;
        u16 hi, lo; fsplit(w, hi, lo);
        wbuf[addr] = hi;
        wbuf[addr + Cin] = lo;
    } else if (bid < 2496) {
        // ---- normalize s[B,16,M] -> xs[N][64] (hi[32]|lo[32], upper 16 zero)
        const int b2 = bid - 2240;
        const int m = (b2 & 7) * 256 + tid;
        const int b = b2 >> 3;
        const float* sp = s + (size_t)b * SDn * Mn + m;
        float v[SDn]; float sq = 0.f;
#pragma unroll
        for (int c = 0; c < SDn; ++c) { v[c] = sp[(size_t)c * Mn]; sq += v[c] * v[c]; }
        const float r = 1.0f / sqrtf(sq);
        unsigned int uh[8], ul[8];
#pragma unroll
        for (int c = 0; c < 8; ++c) {
            u16 h0, l0, h1, l1;
            fsplit(v[2 * c] * r, h0, l0);
            fsplit(v[2 * c + 1] * r, h1, l1);
            uh[c] = (unsigned int)h0 | ((unsigned int)h1 << 16);
            ul[c] = (unsigned int)l0 | ((unsigned int)l1 << 16);
        }
        uint4* xp = (uint4*)(xs + (size_t)(b * Mn + m) * 64);
        xp[0] = make_uint4(uh[0], uh[1], uh[2], uh[3]);
        xp[1] = make_uint4(uh[4], uh[5], uh[6], uh[7]);
        xp[2] = make_uint4(0, 0, 0, 0);
        xp[3] = make_uint4(0, 0, 0, 0);
        xp[4] = make_uint4(ul[0], ul[1], ul[2], ul[3]);
        xp[5] = make_uint4(ul[4], ul[5], ul[6], ul[7]);
        xp[6] = make_uint4(0, 0, 0, 0);
        xp[7] = make_uint4(0, 0, 0, 0);
    } else {
        // ---- zero BN stats (4096 floats) ----
        float4 z4 = {0.f, 0.f, 0.f, 0.f};
        float4* sp4 = (float4*)stats;
#pragma unroll
        for (int k = 0; k < 4; ++k) sp4[tid * 4 + k] = z4;
    }
}

// ---- split fp16 MFMA GEMM: single-buffered A, double-buffered B ------------
// acc0 = Wh*Xh ; accL = Wh*Xl' + Wl'*Xh ; result = acc0 + accL/2048
// LDS <= ~70KB so 2 blocks/CU co-reside (cross-block TLP fills the
// barrier-convoy gaps that dominated at 1 block/CU).
// Schedule (audited): prologue issues A(0),B(0),B(1). Loop ks:
//   wait vmcnt(2*BSEG)  -> drains B(ks)+A(ks), leaves B(ks+1) in flight
//   barrier; ds_read frags; [IBN]; MFMA (3 indep passes); barrier
//   stageA(ks+1) (WAR-safe: frag reads retired); stageB(ks+2, buf ks&1)
// Steady-state age order [B(ks+1), A(ks+1), B(ks+2)] makes the count exact.
// VGPR note: 4x4-frag dual accumulators need ~190 regs -> max 8 waves/block
// (1024-thr config spills catastrophically; measured R5).
// GEOMETRY CONSTRAINT: NT must equal RW*CWv*64 (wave grid == tile). R6's
// c3 <1,2,NT=256> violated this -> waves 2,3 wrote foreign tiles (absmax 5.8).
template<int RW, int CWv, int EPI, int MY, int IBN, int CINT, int NT>
__global__ __launch_bounds__(NT) void mfma_gemm(
    const u16* __restrict__ W, const u16* __restrict__ X, u16* __restrict__ Y,
    const float* __restrict__ bias, const float* __restrict__ zmod,
    const float* __restrict__ statsIn, const float* __restrict__ gin,
    const float* __restrict__ bein, float* __restrict__ stats, int Cout)
{
    static_assert(NT == RW * CWv * 64, "wave grid must exactly cover the tile");
    constexpr int BM = RW * 64, BN = CWv * 64;
    constexpr int ASEG = (BM * 4) / NT;         // A staging iters (4 loads/row)
    constexpr int BSEG = (BN * 4) / NT;         // B staging iters
    constexpr int LMY = (MY == 1) ? 0 : (MY == 2) ? 1 : (MY == 4) ? 2 : 3;
    constexpr int SW = 2 * CINT;
    constexpr int NST = CINT >> 5;              // K-steps
    constexpr int WAITN = 2 * BSEG;             // leave one B step in flight
    constexpr int SSTATN = (EPI == 2) ? (CWv * BM * 2) : 1;
    constexpr int BNN = IBN ? (CINT * 2) : 1;
    constexpr int AUXN = (SSTATN > BNN) ? SSTATN : BNN;
    __shared__ __align__(16) u16 Ah[BM * 32], Al[BM * 32];          // single buf
    __shared__ __align__(16) u16 Bh[2][BN * 32], Bl[2][BN * 32];    // double buf
    __shared__ float saux[AUXN];            // main loop: BN params; epilogue: stats

    const int tid = threadIdx.x;
    const int wave = tid >> 6;
    const int lane = tid & 63;
    const int wm = wave & (RW - 1), wn = wave / RW;
    const int l15 = lane & 15, q = lane >> 4;
    const int lin = blockIdx.x;
    const int xcd = lin & 7;
    const int jj = lin >> 3;
    const int m0 = (jj & (MY - 1)) * BM;
    const int n0 = (xcd + ((jj >> LMY) << 3)) * BN;

    f4v acc0[4][4], accL[4][4];
#pragma unroll
    for (int i = 0; i < 4; ++i)
#pragma unroll
        for (int j = 0; j < 4; ++j) {
            acc0[i][j] = (f4v){0.f, 0.f, 0.f, 0.f};
            accL[i][j] = (f4v){0.f, 0.f, 0.f, 0.f};
        }

    auto stageA = [&](int ks) {
        const int k0 = ks << 5;
#pragma unroll
        for (int s = 0; s < ASEG; ++s) {
            const int flat = s * NT + tid;
            const int row = flat >> 2;
            const int qs = (flat & 3) ^ ((row >> 1) & 3);   // swizzled source chunk
            const u16* ga = W + (size_t)(m0 + row) * SW + k0 + qs * 8;
            gll16(ga, Ah + flat * 8);
            gll16(ga + CINT, Al + flat * 8);
        }
    };
    auto stageB = [&](int ks, int buf) {
        const int k0 = ks << 5;
#pragma unroll
        for (int s = 0; s < BSEG; ++s) {
            const int flat = s * NT + tid;
            const int row = flat >> 2;
            const int qs = (flat & 3) ^ ((row >> 1) & 3);
            const u16* gb = X + (size_t)(n0 + row) * SW + k0 + qs * 8;
            gll16(gb, Bh[buf] + flat * 8);
            gll16(gb + CINT, Bl[buf] + flat * 8);
        }
    };

    if constexpr (IBN) {
        // fused BN finalize: raw (sum,sumsq) + g + be -> (scale, shift) in LDS
        const float inv = 1.0f / (float)Nn;
        for (int c = tid; c < CINT; c += NT) {
            const float mean = statsIn[c * 2] * inv;
            const float var = statsIn[c * 2 + 1] * inv - mean * mean;
            const float sc = gin[c] / sqrtf(var + EPSf);
            saux[c * 2] = sc;
            saux[c * 2 + 1] = fmaf(-mean, sc, bein[c]);
        }
        asm volatile("s_waitcnt vmcnt(0) lgkmcnt(0)" ::: "memory");
    }
    // prologue: A(0) first, then B(0), B(1) -> age order A0,B0,B1
    stageA(0);
    stageB(0, 0);
    if constexpr (NST > 1) stageB(1, 1);

#pragma unroll 1
    for (int ks = 0; ks < NST; ++ks) {
        const int cur = ks & 1;
        if (ks + 1 < NST) {
            asm volatile("s_waitcnt vmcnt(%0)" :: "n"(WAITN) : "memory");
        } else {
            asm volatile("s_waitcnt vmcnt(0)" ::: "memory");
        }
        __builtin_amdgcn_s_barrier();        // all waves' step-ks tiles landed
        __builtin_amdgcn_sched_barrier(0);
        h8v afh[4], afl[4], bfh[4], bfl[4];
#pragma unroll
        for (int i = 0; i < 4; ++i) {
            const int ar = wm * 64 + i * 16 + l15;
            const int ao = ar * 32 + ((q ^ ((ar >> 1) & 3)) << 3);
            afh[i] = *(const h8v*)(Ah + ao);
            afl[i] = *(const h8v*)(Al + ao);
        }
#pragma unroll
        for (int j = 0; j < 4; ++j) {
            const int br = wn * 64 + j * 16 + l15;
            const int bo = br * 32 + ((q ^ ((br >> 1) & 3)) << 3);
            bfh[j] = *(const h8v*)(Bh[cur] + bo);
            bfl[j] = *(const h8v*)(Bl[cur] + bo);
        }
        if constexpr (IBN) {
            // frag elems are LOGICAL channels k0 + q*8 + e; params from LDS
            const int kb = ((ks << 5) + q * 8) * 2;
            const float4 p0 = *(const float4*)(saux + kb);
            const float4 p1 = *(const float4*)(saux + kb + 4);
            const float4 p2 = *(const float4*)(saux + kb + 8);
            const float4 p3 = *(const float4*)(saux + kb + 12);
            const float sc8[8] = {p0.x, p0.z, p1.x, p1.z, p2.x, p2.z, p3.x, p3.z};
            const float sh8[8] = {p0.y, p0.w, p1.y, p1.w, p2.y, p2.w, p3.y, p3.w};
#pragma unroll
            for (int j = 0; j < 4; ++j) {
#pragma unroll
                for (int e = 0; e < 8; ++e) {
                    const float v = (float)bfh[j][e] + (float)bfl[j][e] * LSCI;
                    const float a = fmaxf(fmaf(v, sc8[e], sh8[e]), 0.f);
                    const fp16_t hh = (fp16_t)a;
                    bfh[j][e] = hh;
                    bfl[j][e] = (fp16_t)((a - (float)hh) * LSC);
                }
            }
        }
        __builtin_amdgcn_s_setprio(1);
        // 3 independent passes: no adjacent dependent MFMAs (16 ops apart);
        // per-accumulator order preserved (accL: term1 then term2).
#pragma unroll
        for (int i = 0; i < 4; ++i)
#pragma unroll
            for (int j = 0; j < 4; ++j)
                accL[i][j] = __builtin_amdgcn_mfma_f32_16x16x32_f16(afh[i], bfl[j], accL[i][j], 0, 0, 0);
#pragma unroll
        for (int i = 0; i < 4; ++i)
#pragma unroll
            for (int j = 0; j < 4; ++j)
                acc0[i][j] = __builtin_amdgcn_mfma_f32_16x16x32_f16(afh[i], bfh[j], acc0[i][j], 0, 0, 0);
#pragma unroll
        for (int i = 0; i < 4; ++i)
#pragma unroll
            for (int j = 0; j < 4; ++j)
                accL[i][j] = __builtin_amdgcn_mfma_f32_16x16x32_f16(afl[i], bfh[j], accL[i][j], 0, 0, 0);
        __builtin_amdgcn_s_setprio(0);
        __builtin_amdgcn_s_barrier();        // frag reads retired -> overwrite safe
        if (ks + 1 < NST) stageA(ks + 1);    // single-buf A: depth-1 prefetch
        if (ks + 2 < NST) stageB(ks + 2, cur);
    }

    // ---- epilogue ----
    float* sstat = saux;
    const int bb = n0 >> 11;
    const int SY = 2 * Cout;
#pragma unroll
    for (int i = 0; i < 4; ++i) {
        const int chb = m0 + wm * 64 + i * 16 + q * 4;
        const float4 bias4 = *(const float4*)(bias + chb);
        float z0 = 0.f, z1 = 0.f, z2 = 0.f, z3 = 0.f;
        if constexpr (EPI == 1) {
            const float4 z4 = *(const float4*)(zmod + bb * CWn + chb);
            z0 = z4.x; z1 = z4.y; z2 = z4.z; z3 = z4.w;
        }
        float ssum[4] = {0.f, 0.f, 0.f, 0.f}, ssq[4] = {0.f, 0.f, 0.f, 0.f};
#pragma unroll
        for (int j = 0; j < 4; ++j) {
            const int n = n0 + wn * 64 + j * 16 + l15;
            float v0 = fmaf(accL[i][j][0], LSCI, acc0[i][j][0]) + bias4.x;
            float v1 = fmaf(accL[i][j][1], LSCI, acc0[i][j][1]) + bias4.y;
            float v2 = fmaf(accL[i][j][2], LSCI, acc0[i][j][2]) + bias4.z;
            float v3 = fmaf(accL[i][j][3], LSCI, acc0[i][j][3]) + bias4.w;
            if constexpr (EPI == 0) {
                v0 = fmaxf(v0, 0.f); v1 = fmaxf(v1, 0.f); v2 = fmaxf(v2, 0.f); v3 = fmaxf(v3, 0.f);
            } else if constexpr (EPI == 1) {
                v0 = fminf(fmaxf(v0, -1.f), 1.f) * z0;
                v1 = fminf(fmaxf(v1, -1.f), 1.f) * z1;
                v2 = fminf(fmaxf(v2, -1.f), 1.f) * z2;
                v3 = fminf(fmaxf(v3, -1.f), 1.f) * z3;
            } else {
                ssum[0] += v0; ssum[1] += v1; ssum[2] += v2; ssum[3] += v3;
                ssq[0] += v0 * v0; ssq[1] += v1 * v1; ssq[2] += v2 * v2; ssq[3] += v3 * v3;
            }
            u16 h0, l0, h1, l1, h2, l2, h3, l3;
            fsplit(v0, h0, l0); fsplit(v1, h1, l1);
            fsplit(v2, h2, l2); fsplit(v3, h3, l3);
            ushort4 hv = {h0, h1, h2, h3};
            ushort4 lv = {l0, l1, l2, l3};
            u16* yp = Y + (size_t)n * SY + chb;
            *(ushort4*)yp = hv;
            *(ushort4*)(yp + Cout) = lv;
        }
        if constexpr (EPI == 2) {
#pragma unroll
            for (int r = 0; r < 4; ++r) {
#pragma unroll
                for (int d = 1; d < 16; d <<= 1) {
                    ssum[r] += __shfl_xor(ssum[r], d);
                    ssq[r]  += __shfl_xor(ssq[r], d);
                }
            }
            if (l15 == 0) {
                const int chl = wm * 64 + i * 16 + q * 4;
#pragma unroll
                for (int r = 0; r < 4; ++r) {
                    sstat[(wn * BM + chl + r) * 2]     = ssum[r];
                    sstat[(wn * BM + chl + r) * 2 + 1] = ssq[r];
                }
            }
        }
    }
    if constexpr (EPI == 2) {
        __syncthreads();
        if (tid < BM) {
            float s0 = 0.f, s1 = 0.f;
#pragma unroll
            for (int w = 0; w < CWv; ++w) {
                s0 += sstat[(w * BM + tid) * 2];
                s1 += sstat[(w * BM + tid) * 2 + 1];
            }
            atomicAdd(&stats[(m0 + tid) * 2], s0);
            atomicAdd(&stats[(m0 + tid) * 2 + 1], s1);
        }
    }
}

// ---- final 64->3 conv (fused BN finalize + BN+ReLU on split input) ---------
__global__ __launch_bounds__(256) void finalconv_pm(
    const u16* __restrict__ y3, const float* __restrict__ statsIn,
    const float* __restrict__ gin, const float* __restrict__ bein,
    const float* __restrict__ wout, const float* __restrict__ bout,
    float* __restrict__ pts)
{
    __shared__ float swo[3][64];
    __shared__ float ssc[64], ssh[64];
    const int tid = threadIdx.x;
    if (tid < 192) swo[tid / 64][tid % 64] = wout[tid];
    if (tid < 64) {
        // fused c3 BN finalize (identical op order to old finalize_kernel)
        const float inv = 1.0f / (float)Nn;
        const float mean = statsIn[tid * 2] * inv;
        const float var = statsIn[tid * 2 + 1] * inv - mean * mean;
        const float sc = gin[tid] / sqrtf(var + EPSf);
        ssc[tid] = sc;
        ssh[tid] = fmaf(-mean, sc, bein[tid]);
    }
    __syncthreads();
    const int n = blockIdx.x * 256 + tid;
    const uint4* yph = (const uint4*)(y3 + (size_t)n * 128);
    float d0 = bout[0], d1 = bout[1], d2 = bout[2];
#pragma unroll
    for (int cc = 0; cc < 8; ++cc) {
        const uint4 H = yph[cc];
        const uint4 L = yph[8 + cc];
        const unsigned hu[4] = {H.x, H.y, H.z, H.w};
        const unsigned lu[4] = {L.x, L.y, L.z, L.w};
#pragma unroll
        for (int e = 0; e < 4; ++e) {
            const int c = cc * 8 + e * 2;
            const float v0 = fjoin((u16)(hu[e] & 0xffff), (u16)(lu[e] & 0xffff));
            const float v1 = fjoin((u16)(hu[e] >> 16), (u16)(lu[e] >> 16));
            const float a0 = fmaxf(fmaf(v0, ssc[c], ssh[c]), 0.f);
            const float a1 = fmaxf(fmaf(v1, ssc[c + 1], ssh[c + 1]), 0.f);
            d0 = fmaf(a0, swo[0][c], d0); d0 = fmaf(a1, swo[0][c + 1], d0);
            d1 = fmaf(a0, swo[1][c], d1); d1 = fmaf(a1, swo[1][c + 1], d1);
            d2 = fmaf(a0, swo[2][c], d2); d2 = fmaf(a1, swo[2][c + 1], d2);
        }
    }
    float4 p = {d0, d1, d2, d0 * d0 + d1 * d1 + d2 * d2};
    *(float4*)(pts + (size_t)n * 4) = p;
}

// ---- graph filtering: 16 threads/point, packed u32 keys --------------------
__global__ __launch_bounds__(512) void knn_kernel(const float* __restrict__ pts,
                                                  float* __restrict__ out) {
    __shared__ __align__(16) float4 sp[Mn];   // 32 KB -> 4 blocks/CU (wave cap)
    const int b = blockIdx.y;
    const int tid = threadIdx.x;
    const float4* pb = (const float4*)pts + (size_t)b * Mn;
    for (int i = tid; i < Mn; i += 512) sp[i] = pb[i];
    __syncthreads();
    const int lane = tid & 63;
    const int wv = tid >> 6;                    // 0..7
    const int seg = lane & 15;                  // segment 0..15 (128 cands each)
    const int ptl = (wv << 2) | (lane >> 4);    // point-local 0..31
    const int m = blockIdx.x * 32 + ptl;
    const float4 p = sp[m];
    // self-exclusion: only the owning segment can ever match (tt <= 127 < 128)
    const int cself = (seg == (m >> 7)) ? (m & 127) : 128;
    const int nb = seg << 7;
    unsigned bk[8];
#pragma unroll
    for (int k = 0; k < 8; ++k) bk[k] = 0xFFFFFFFFu;
    for (int t = 0; t < 128; ++t) {
        const int tt = (t + seg) & 127;         // stagger start by seg (bank tiling)
        const float4 q = sp[nb | tt];
        const float dot = fmaf(p.x, q.x, fmaf(p.y, q.y, p.z * q.z));
        float d = fmaf(-2.f, dot, q.w + p.w);   // true squared distance (+-ulp)
        d = fmaxf(d, 0.f);                      // keep uint-monotone (sign bit off)
        unsigned key = (__float_as_uint(d) & 0xFFFFFF80u) | (unsigned)tt;
        key = (tt == cself) ? 0xFFFFFFFFu : key;
        // branchless sorted insert, min/max only
        bk[7] = umin(bk[7], key);
#pragma unroll
        for (int k = 6; k >= 0; --k) {
            const unsigned lo = umin(bk[k], bk[k + 1]);
            bk[k + 1] = umax(bk[k], bk[k + 1]);
            bk[k] = lo;
        }
    }
    // keep originals for index recovery after the merge
    unsigned ok[8];
#pragma unroll
    for (int k = 0; k < 8; ++k) ok[k] = bk[k];
    // 4 bitonic merge rounds across the 16-lane group (partner = lane ^ r)
#pragma unroll
    for (int r = 1; r <= 8; r <<= 1) {
        unsigned od[8], md[8];
#pragma unroll
        for (int k = 0; k < 8; ++k) od[k] = (unsigned)__shfl_xor((int)bk[k], r);
#pragma unroll
        for (int k = 0; k < 8; ++k) md[k] = umin(bk[k], od[7 - k]);  // lowest-8 of union
#define CSU(a, c) { const unsigned lo_ = umin(md[a], md[c]); md[c] = umax(md[a], md[c]); md[a] = lo_; }
        CSU(0,4); CSU(1,5); CSU(2,6); CSU(3,7);
        CSU(0,2); CSU(1,3); CSU(4,6); CSU(5,7);
        CSU(0,1); CSU(2,3); CSU(4,5); CSU(6,7);
#undef CSU
#pragma unroll
        for (int k = 0; k < 8; ++k) bk[k] = md[k];
    }
    const unsigned TK = bk[7];                  // global 8th-smallest key
    // recovery: scan own 8 survivors vs TK; strict-less + equal-blend
    float slt[4] = {0.f, 0.f, 0.f, 0.f};        // x, y, z, count (key < TK)
    float seq[4] = {0.f, 0.f, 0.f, 0.f};        // x, y, z, count (key == TK)
#pragma unroll
    for (int k = 0; k < 8; ++k) {
        const unsigned key = ok[k];
        const float4 q = sp[nb | (int)(key & 127u)];
        const bool lt = key < TK;
        const bool eq = key == TK;
        slt[0] += lt ? q.x : 0.f; slt[1] += lt ? q.y : 0.f;
        slt[2] += lt ? q.z : 0.f; slt[3] += lt ? 1.f : 0.f;
        seq[0] += eq ? q.x : 0.f; seq[1] += eq ? q.y : 0.f;
        seq[2] += eq ? q.z : 0.f; seq[3] += eq ? 1.f : 0.f;
    }
#pragma unroll
    for (int r = 1; r <= 8; r <<= 1) {
#pragma unroll
        for (int k = 0; k < 4; ++k) {
            slt[k] += __shfl_xor(slt[k], r);
            seq[k] += __shfl_xor(seq[k], r);
        }
    }
    if (seg == 0) {
        const float scale = (8.f - slt[3]) / seq[3];   // seq[3] >= 1 guaranteed
        const float nx = fmaf(scale, seq[0], slt[0]);
        const float ny = fmaf(scale, seq[1], slt[1]);
        const float nz = fmaf(scale, seq[2], slt[2]);
        const float s8 = 0.125f;
        float* ob = out + (size_t)b * 3 * Mn;
        ob[m]          = 2.f * p.x - nx * s8;
        ob[Mn + m]     = 2.f * p.y - ny * s8;
        ob[2 * Mn + m] = 2.f * p.z - nz * s8;
    }
}

// ============================================================================
extern "C" void kernel_launch(void* const* d_in, const int* in_sizes, int n_in,
                              void* d_out, int out_size, void* d_ws, size_t ws_size,
                              hipStream_t stream)
{
    (void)in_sizes; (void)n_in; (void)out_size;
    const float* z     = (const float*)d_in[0];
    const float* s     = (const float*)d_in[1];
    const float* w_m1  = (const float*)d_in[2];
    const float* b_m1  = (const float*)d_in[3];
    const float* w_m2  = (const float*)d_in[4];
    const float* b_m2  = (const float*)d_in[5];
    const float* w_out = (const float*)d_in[6];
    const float* b_out = (const float*)d_in[7];
    const float* w_c[4]  = {(const float*)d_in[8],  (const float*)d_in[12], (const float*)d_in[16], (const float*)d_in[20]};
    const float* b_c[4]  = {(const float*)d_in[9],  (const float*)d_in[13], (const float*)d_in[17], (const float*)d_in[21]};
    const float* g_c[4]  = {(const float*)d_in[10], (const float*)d_in[14], (const float*)d_in[18], (const float*)d_in[22]};
    const float* be_c[4] = {(const float*)d_in[11], (const float*)d_in[15], (const float*)d_in[19], (const float*)d_in[23]};

    char* ws = (char*)d_ws;
    const size_t MB = 1024ull * 1024ull;
    float* outp = (float*)d_out;
    if (ws_size < 208 * MB) return;   // proven: harness provides >= 208 MiB

    // -------- split-fp16 MFMA path (peak 204 MiB) --------
    u16*   wbuf  = (u16*)ws;
    float* stats = (float*)(ws + 3 * MB);
    u16*   xs  = (u16*)(ws + 4 * MB);
    u16*   x1  = (u16*)(ws + 12 * MB);
    u16*   x2  = (u16*)(ws + 76 * MB);
    u16*   y0  = (u16*)(ws + 12 * MB);   // contiguous after both chunks (RAW)
    u16*   y0a = (u16*)(ws + 12 * MB);   // rows [0, 32K)
    u16*   y0b = (u16*)(ws + 76 * MB);   // rows [32K, 64K)
    u16*   y1  = (u16*)(ws + 140 * MB);  // RAW c1 output
    u16*   y2  = (u16*)(ws + 12 * MB);   // RAW c2 output
    u16*   y3  = (u16*)(ws + 76 * MB);   // RAW c3 output
    float* pts = (float*)(ws + 4 * MB);

    prep_kernel<<<2497, 256, 0, stream>>>(w_m1, w_m2, w_c[0], w_c[1], w_c[2], w_c[3], s, wbuf, xs, stats);
    // m1: [N][32] -> [N][256]  (128x128, 256 thr; 1024 blocks)
    mfma_gemm<2, 2, 0, 2, 0, 32, 256><<<1024, 256, 0, stream>>>(wbuf, xs, x1, b_m1, nullptr, nullptr, nullptr, nullptr, nullptr, 256);
    // m2: [N][256] -> [N][512] (256x128, 512 thr, ~68KB LDS -> 2 blk/CU; 1024 blocks)
    mfma_gemm<4, 2, 1, 2, 0, 256, 512><<<1024, 512, 0, stream>>>(wbuf + 16384, x1, x2, b_m2, z, nullptr, nullptr, nullptr, nullptr, 512);
    // c0 a/b: rows halves (256x128; 512 blocks each) -> RAW y0 + stats
    // (NOT mergeable: y0b overwrites x2 rows [0,32K) which c0a reads -> sequential)
    mfma_gemm<4, 2, 2, 2, 0, 512, 512><<<512, 512, 0, stream>>>(wbuf + 278528, x2, y0a, b_c[0], nullptr, nullptr, nullptr, nullptr, stats + 0, 512);
    mfma_gemm<4, 2, 2, 2, 0, 512, 512><<<512, 512, 0, stream>>>(wbuf + 278528, x2 + (size_t)Hn * 1024, y0b, b_c[0], nullptr, nullptr, nullptr, nullptr, stats + 0, 512);
    // c1: BN0 finalize fused (256x128, MY=1 -> 512 blocks); RAW y1 + stats
    mfma_gemm<4, 2, 2, 1, 1, 512, 512><<<512, 512, 0, stream>>>(wbuf + 802816, y0, y1, b_c[1], nullptr, stats + 0, g_c[0], be_c[0], stats + 1024, 256);
    // c2: BN1 finalize fused (128x128, 256 thr, ~50KB -> 3 blk/CU; 512 blocks); RAW y2 + stats
    mfma_gemm<2, 2, 2, 1, 1, 256, 256><<<512, 256, 0, stream>>>(wbuf + 1064960, y1, y2, b_c[2], nullptr, stats + 1024, g_c[1], be_c[1], stats + 2048, 128);
    // c3: BN2 finalize fused (64x256, 256 thr = 1x4 wave grid; 256 blocks); RAW y3 + stats
    mfma_gemm<1, 4, 2, 1, 1, 128, 256><<<256, 256, 0, stream>>>(wbuf + 1130496, y2, y3, b_c[3], nullptr, stats + 2048, g_c[2], be_c[2], stats + 3072, 64);
    // finalconv: BN3 finalize fused from stats+3072
    finalconv_pm<<<Nn / 256, 256, 0, stream>>>(y3, stats + 3072, g_c[3], be_c[3], w_out, b_out, pts);
    knn_kernel<<<dim3(Mn / 32, Bn), 512, 0, stream>>>(pts, outp);
}

// Round 9
// 537.895 us; speedup vs baseline: 4.1442x; 1.1746x over previous
//
#include <hip/hip_runtime.h>
#include <math.h>

#define Bn 32
#define Mn 2048
#define Nn 65536      // Bn * Mn
#define Hn 32768      // Nn / 2 (chunk for race-free c0)
#define SDn 16
#define CWn 512
#define EPSf 1e-5f
#define KGF 8
#define WTOT 573440   // logical weight elements
#define LSC 2048.0f   // lo-plane scale (2^11)
#define LSCI (1.0f / 2048.0f)

typedef unsigned short u16;
typedef _Float16 fp16_t;
typedef __attribute__((ext_vector_type(8))) _Float16 h8v;  // MFMA A/B frag: 8 f16
typedef __attribute__((ext_vector_type(4))) float f4v;     // MFMA C/D frag: 4 fp32

__device__ __forceinline__ u16 f2h(float f) {
    union { fp16_t h; u16 u; } c; c.h = (fp16_t)f; return c.u;
}
__device__ __forceinline__ float h2f(u16 u) {
    union { fp16_t h; u16 u; } c; c.u = u; return (float)c.h;
}
__device__ __forceinline__ void fsplit(float f, u16& hi, u16& lo) {
    hi = f2h(f);
    lo = f2h((f - h2f(hi)) * LSC);
}
__device__ __forceinline__ float fjoin(u16 hi, u16 lo) {
    return h2f(hi) + h2f(lo) * LSCI;
}
// async global->LDS, 16 bytes/lane (dest must be wave-uniform base + lane*16)
__device__ __forceinline__ void gll16(const u16* g, u16* l) {
    __builtin_amdgcn_global_load_lds((const __attribute__((address_space(1))) void*)g,
                                     (__attribute__((address_space(3))) void*)l, 16, 0, 0);
}
__device__ __forceinline__ unsigned umin(unsigned a, unsigned b) { return a < b ? a : b; }
__device__ __forceinline__ unsigned umax(unsigned a, unsigned b) { return a > b ? a : b; }

// ============================================================================
// prep: weights fp32 -> split layout, normalize s -> xs, zero stats (fused)
// ============================================================================
__global__ __launch_bounds__(256) void prep_kernel(
    const float* __restrict__ wm1, const float* __restrict__ wm2,
    const float* __restrict__ wc0, const float* __restrict__ wc1,
    const float* __restrict__ wc2, const float* __restrict__ wc3,
    const float* __restrict__ s,
    u16* __restrict__ wbuf, u16* __restrict__ xs, float* __restrict__ stats)
{
    const int bid = blockIdx.x;
    const int tid = threadIdx.x;
    if (bid < 2240) {
        // ---- weight conversion: [Cout][hi[Cin] | lo[Cin]] ----
        int i = bid * 256 + tid;
        float w; int r, k, Cin; size_t base;
        if (i < 8192) {                              // m1 padded [256][32]
            r = i >> 5; k = i & 31; Cin = 32; base = 0;
            w = (k < SDn) ? wm1[r * SDn + k] : 0.f;
        } else {
            int j = i - 8192;
            if (j < 131072)                    { r = j >> 8; k = j & 255; Cin = 256; base = 16384;   w = wm2[j]; }
            else if ((j -= 131072) < 262144)   { r = j >> 9; k = j & 511; Cin = 512; base = 278528;  w = wc0[j]; }
            else if ((j -= 262144) < 131072)   { r = j >> 9; k = j & 511; Cin = 512; base = 802816;  w = wc1[j]; }
            else if ((j -= 131072) < 32768)    { r = j >> 8; k = j & 255; Cin = 256; base = 1064960; w = wc2[j]; }
            else { j -= 32768;                   r = j >> 7; k = j & 127; Cin = 128; base = 1130496; w = wc3[j]; }
        }
        const size_t addr = base + (size_t)r * (2 * Cin) + k;
        u16 hi, lo; fsplit(w, hi, lo);
        wbuf[addr] = hi;
        wbuf[addr + Cin] = lo;
    } else if (bid < 2496) {
        // ---- normalize s[B,16,M] -> xs[N][64] (hi[32]|lo[32], upper 16 zero)
        const int b2 = bid - 2240;
        const int m = (b2 & 7) * 256 + tid;
        const int b = b2 >> 3;
        const float* sp = s + (size_t)b * SDn * Mn + m;
        float v[SDn]; float sq = 0.f;
#pragma unroll
        for (int c = 0; c < SDn; ++c) { v[c] = sp[(size_t)c * Mn]; sq += v[c] * v[c]; }
        const float r = 1.0f / sqrtf(sq);
        unsigned int uh[8], ul[8];
#pragma unroll
        for (int c = 0; c < 8; ++c) {
            u16 h0, l0, h1, l1;
            fsplit(v[2 * c] * r, h0, l0);
            fsplit(v[2 * c + 1] * r, h1, l1);
            uh[c] = (unsigned int)h0 | ((unsigned int)h1 << 16);
            ul[c] = (unsigned int)l0 | ((unsigned int)l1 << 16);
        }
        uint4* xp = (uint4*)(xs + (size_t)(b * Mn + m) * 64);
        xp[0] = make_uint4(uh[0], uh[1], uh[2], uh[3]);
        xp[1] = make_uint4(uh[4], uh[5], uh[6], uh[7]);
        xp[2] = make_uint4(0, 0, 0, 0);
        xp[3] = make_uint4(0, 0, 0, 0);
        xp[4] = make_uint4(ul[0], ul[1], ul[2], ul[3]);
        xp[5] = make_uint4(ul[4], ul[5], ul[6], ul[7]);
        xp[6] = make_uint4(0, 0, 0, 0);
        xp[7] = make_uint4(0, 0, 0, 0);
    } else {
        // ---- zero BN stats (4096 floats) ----
        float4 z4 = {0.f, 0.f, 0.f, 0.f};
        float4* sp4 = (float4*)stats;
#pragma unroll
        for (int k = 0; k < 4; ++k) sp4[tid * 4 + k] = z4;
    }
}

// ---- split fp16 MFMA GEMM, full double-buffered pipeline (R5-proven) -------
// acc0 = Wh*Xh ; accL = Wh*Xl' + Wl'*Xh ; result = acc0 + accL/2048
// Both A and B tiles double-buffered; stage(ks+2) issued after compute(ks),
// per-step wait is COUNTED vmcnt(VMSTEP); never vmcnt(0) mid-loop.
// NEW (R8): LDS-bounce epilogue -- per j-pass, frags are fsplit into a padded
// LDS tile, then streamed out as fully-coalesced 16B stores. Replaces the
// 8B/lane scatter stores (64 cache lines per instruction) with contiguous
// 512B spans. Same arithmetic, same per-channel summation order for stats.
// GEOMETRY CONSTRAINT: NT must equal RW*CWv*64 (wave grid == tile) -- R6's
// violation wrote foreign tiles.
template<int RW, int CWv, int EPI, int MY, int IBN, int CINT, int NT>
__global__ __launch_bounds__(NT) void mfma_gemm(
    const u16* __restrict__ W, const u16* __restrict__ X, u16* __restrict__ Y,
    const float* __restrict__ bias, const float* __restrict__ zmod,
    const float* __restrict__ statsIn, const float* __restrict__ gin,
    const float* __restrict__ bein, float* __restrict__ stats, int Cout)
{
    static_assert(NT == RW * CWv * 64, "wave grid must exactly cover the tile");
    constexpr int BM = RW * 64, BN = CWv * 64;
    constexpr int ASEG = (BM * 4) / NT;         // A staging iters (4 loads/row)
    constexpr int BSEG = (BN * 4) / NT;         // B staging iters
    constexpr int LMY = (MY == 1) ? 0 : (MY == 2) ? 1 : (MY == 4) ? 2 : 3;
    constexpr int SW = 2 * CINT;
    constexpr int NST = CINT >> 5;              // K-steps
    constexpr int VMSTEP = 2 * ASEG + 2 * BSEG; // gll16 per thread per step
    constexpr int SSTATN = (EPI == 2) ? (CWv * BM * 2) : 1;
    constexpr int BNN = IBN ? (CINT * 2) : 1;
    constexpr int AUXN = (SSTATN > BNN) ? SSTATN : BNN;
    constexpr int BSTR = 2 * BM + 8;            // bounce row stride (u16), pad kills bank conflicts
    constexpr int BROWS = CWv * 16;             // n-rows per j-pass
    constexpr int UNITS = BROWS * 2 * (BM / 8); // 16B store units per pass
    static_assert(UNITS % NT == 0, "store units must tile the block");
    __shared__ __align__(16) u16 Ah[2][BM * 32], Al[2][BM * 32];
    __shared__ __align__(16) u16 Bh[2][BN * 32], Bl[2][BN * 32];
    __shared__ __align__(16) u16 bounce[BROWS * BSTR];
    __shared__ float saux[AUXN];            // main loop: BN params; epilogue: stats

    const int tid = threadIdx.x;
    const int wave = tid >> 6;
    const int lane = tid & 63;
    const int wm = wave & (RW - 1), wn = wave / RW;
    const int l15 = lane & 15, q = lane >> 4;
    const int lin = blockIdx.x;
    const int xcd = lin & 7;
    const int jj = lin >> 3;
    const int m0 = (jj & (MY - 1)) * BM;
    const int n0 = (xcd + ((jj >> LMY) << 3)) * BN;

    f4v acc0[4][4], accL[4][4];
#pragma unroll
    for (int i = 0; i < 4; ++i)
#pragma unroll
        for (int j = 0; j < 4; ++j) {
            acc0[i][j] = (f4v){0.f, 0.f, 0.f, 0.f};
            accL[i][j] = (f4v){0.f, 0.f, 0.f, 0.f};
        }

    // ---- staging: one full K-step (A + B, both planes) into buffer `buf` ----
    auto stageAB = [&](int ks, int buf) {
        const int k0 = ks << 5;
#pragma unroll
        for (int s = 0; s < ASEG; ++s) {
            const int flat = s * NT + tid;
            const int row = flat >> 2;
            const int qs = (flat & 3) ^ ((row >> 1) & 3);   // swizzled source chunk
            const u16* ga = W + (size_t)(m0 + row) * SW + k0 + qs * 8;
            gll16(ga, Ah[buf] + flat * 8);
            gll16(ga + CINT, Al[buf] + flat * 8);
        }
#pragma unroll
        for (int s = 0; s < BSEG; ++s) {
            const int flat = s * NT + tid;
            const int row = flat >> 2;
            const int qs = (flat & 3) ^ ((row >> 1) & 3);
            const u16* gb = X + (size_t)(n0 + row) * SW + k0 + qs * 8;
            gll16(gb, Bh[buf] + flat * 8);
            gll16(gb + CINT, Bl[buf] + flat * 8);
        }
    };

    if constexpr (IBN) {
        // fused BN finalize: raw (sum,sumsq) + g + be -> (scale, shift) in LDS
        const float inv = 1.0f / (float)Nn;
        for (int c = tid; c < CINT; c += NT) {
            const float mean = statsIn[c * 2] * inv;
            const float var = statsIn[c * 2 + 1] * inv - mean * mean;
            const float sc = gin[c] / sqrtf(var + EPSf);
            saux[c * 2] = sc;
            saux[c * 2 + 1] = fmaf(-mean, sc, bein[c]);
        }
        asm volatile("s_waitcnt vmcnt(0) lgkmcnt(0)" ::: "memory");
    }
    stageAB(0, 0);                           // prologue: two steps in flight
    if constexpr (NST > 1) stageAB(1, 1);

#pragma unroll 1
    for (int ks = 0; ks < NST; ++ks) {
        const int cur = ks & 1;
        if (ks + 1 < NST) {
            // step ks landed; step ks+1 stays in flight across this compute
            asm volatile("s_waitcnt vmcnt(%0)" :: "n"(VMSTEP) : "memory");
        } else {
            asm volatile("s_waitcnt vmcnt(0)" ::: "memory");
        }
        __builtin_amdgcn_s_barrier();        // all waves' cur-tile loads landed
        __builtin_amdgcn_sched_barrier(0);
        h8v afh[4], afl[4], bfh[4], bfl[4];
#pragma unroll
        for (int i = 0; i < 4; ++i) {
            const int ar = wm * 64 + i * 16 + l15;
            const int ao = ar * 32 + ((q ^ ((ar >> 1) & 3)) << 3);
            afh[i] = *(const h8v*)(Ah[cur] + ao);
            afl[i] = *(const h8v*)(Al[cur] + ao);
        }
#pragma unroll
        for (int j = 0; j < 4; ++j) {
            const int br = wn * 64 + j * 16 + l15;
            const int bo = br * 32 + ((q ^ ((br >> 1) & 3)) << 3);
            bfh[j] = *(const h8v*)(Bh[cur] + bo);
            bfl[j] = *(const h8v*)(Bl[cur] + bo);
        }
        if constexpr (IBN) {
            // frag elems are LOGICAL channels k0 + q*8 + e; params from LDS
            const int kb = ((ks << 5) + q * 8) * 2;
            const float4 p0 = *(const float4*)(saux + kb);
            const float4 p1 = *(const float4*)(saux + kb + 4);
            const float4 p2 = *(const float4*)(saux + kb + 8);
            const float4 p3 = *(const float4*)(saux + kb + 12);
            const float sc8[8] = {p0.x, p0.z, p1.x, p1.z, p2.x, p2.z, p3.x, p3.z};
            const float sh8[8] = {p0.y, p0.w, p1.y, p1.w, p2.y, p2.w, p3.y, p3.w};
#pragma unroll
            for (int j = 0; j < 4; ++j) {
#pragma unroll
                for (int e = 0; e < 8; ++e) {
                    const float v = (float)bfh[j][e] + (float)bfl[j][e] * LSCI;
                    const float a = fmaxf(fmaf(v, sc8[e], sh8[e]), 0.f);
                    const fp16_t hh = (fp16_t)a;
                    bfh[j][e] = hh;
                    bfl[j][e] = (fp16_t)((a - (float)hh) * LSC);
                }
            }
        }
        __builtin_amdgcn_s_setprio(1);
        // 3 independent passes: no adjacent dependent MFMAs (16 ops apart);
        // per-accumulator order preserved (accL: term1 then term2).
#pragma unroll
        for (int i = 0; i < 4; ++i)
#pragma unroll
            for (int j = 0; j < 4; ++j)
                accL[i][j] = __builtin_amdgcn_mfma_f32_16x16x32_f16(afh[i], bfl[j], accL[i][j], 0, 0, 0);
#pragma unroll
        for (int i = 0; i < 4; ++i)
#pragma unroll
            for (int j = 0; j < 4; ++j)
                acc0[i][j] = __builtin_amdgcn_mfma_f32_16x16x32_f16(afh[i], bfh[j], acc0[i][j], 0, 0, 0);
#pragma unroll
        for (int i = 0; i < 4; ++i)
#pragma unroll
            for (int j = 0; j < 4; ++j)
                accL[i][j] = __builtin_amdgcn_mfma_f32_16x16x32_f16(afl[i], bfh[j], accL[i][j], 0, 0, 0);
        __builtin_amdgcn_s_setprio(0);
        __builtin_amdgcn_s_barrier();        // frag reads retired -> overwrite safe
        if (ks + 2 < NST) stageAB(ks + 2, cur);
    }

    // ---- epilogue: j-pass LDS bounce -> coalesced stores ----
    float* sstat = saux;
    const int bb = n0 >> 11;
    const int SY = 2 * Cout;
    float ssum[4][4], ssq[4][4];
    if constexpr (EPI == 2) {
#pragma unroll
        for (int i = 0; i < 4; ++i)
#pragma unroll
            for (int r = 0; r < 4; ++r) { ssum[i][r] = 0.f; ssq[i][r] = 0.f; }
    }
    const int nl_w = wn * 16 + l15;               // bounce row this thread writes
#pragma unroll
    for (int j = 0; j < 4; ++j) {
        __builtin_amdgcn_s_barrier();             // prev pass's reads of bounce done
#pragma unroll
        for (int i = 0; i < 4; ++i) {
            const int chb = m0 + wm * 64 + i * 16 + q * 4;
            const float4 bias4 = *(const float4*)(bias + chb);
            float v0 = fmaf(accL[i][j][0], LSCI, acc0[i][j][0]) + bias4.x;
            float v1 = fmaf(accL[i][j][1], LSCI, acc0[i][j][1]) + bias4.y;
            float v2 = fmaf(accL[i][j][2], LSCI, acc0[i][j][2]) + bias4.z;
            float v3 = fmaf(accL[i][j][3], LSCI, acc0[i][j][3]) + bias4.w;
            if constexpr (EPI == 0) {
                v0 = fmaxf(v0, 0.f); v1 = fmaxf(v1, 0.f); v2 = fmaxf(v2, 0.f); v3 = fmaxf(v3, 0.f);
            } else if constexpr (EPI == 1) {
                const float4 z4 = *(const float4*)(zmod + bb * CWn + chb);
                v0 = fminf(fmaxf(v0, -1.f), 1.f) * z4.x;
                v1 = fminf(fmaxf(v1, -1.f), 1.f) * z4.y;
                v2 = fminf(fmaxf(v2, -1.f), 1.f) * z4.z;
                v3 = fminf(fmaxf(v3, -1.f), 1.f) * z4.w;
            } else {
                ssum[i][0] += v0; ssum[i][1] += v1; ssum[i][2] += v2; ssum[i][3] += v3;
                ssq[i][0] += v0 * v0; ssq[i][1] += v1 * v1; ssq[i][2] += v2 * v2; ssq[i][3] += v3 * v3;
            }
            u16 h0, l0, h1, l1, h2, l2, h3, l3;
            fsplit(v0, h0, l0); fsplit(v1, h1, l1);
            fsplit(v2, h2, l2); fsplit(v3, h3, l3);
            const ushort4 hv = {h0, h1, h2, h3};
            const ushort4 lv = {l0, l1, l2, l3};
            const int chl = wm * 64 + i * 16 + q * 4;     // ch within BM
            *(ushort4*)(bounce + nl_w * BSTR + chl) = hv;
            *(ushort4*)(bounce + nl_w * BSTR + BM + chl) = lv;
        }
        __builtin_amdgcn_s_barrier();             // bounce tile complete
        // coalesced store: BROWS rows x {hi,lo} x BM u16 (512B spans per row)
#pragma unroll
        for (int u0 = 0; u0 < UNITS; u0 += NT) {
            const int u = u0 + tid;
            const int nl = u / (2 * (BM / 8));
            const int rem = u % (2 * (BM / 8));
            const int plane = rem / (BM / 8);
            const int off8 = rem % (BM / 8);
            const int n = n0 + (nl >> 4) * 64 + j * 16 + (nl & 15);
            u16* yp = Y + (size_t)n * SY + (plane ? Cout : 0) + m0 + off8 * 8;
            *(uint4*)yp = *(const uint4*)(bounce + nl * BSTR + plane * BM + off8 * 8);
        }
    }
    if constexpr (EPI == 2) {
#pragma unroll
        for (int i = 0; i < 4; ++i) {
#pragma unroll
            for (int r = 0; r < 4; ++r) {
#pragma unroll
                for (int d = 1; d < 16; d <<= 1) {
                    ssum[i][r] += __shfl_xor(ssum[i][r], d);
                    ssq[i][r]  += __shfl_xor(ssq[i][r], d);
                }
            }
            if (l15 == 0) {
                const int chl = wm * 64 + i * 16 + q * 4;
#pragma unroll
                for (int r = 0; r < 4; ++r) {
                    sstat[(wn * BM + chl + r) * 2]     = ssum[i][r];
                    sstat[(wn * BM + chl + r) * 2 + 1] = ssq[i][r];
                }
            }
        }
        __syncthreads();
        if (tid < BM) {
            float s0 = 0.f, s1 = 0.f;
#pragma unroll
            for (int w = 0; w < CWv; ++w) {
                s0 += sstat[(w * BM + tid) * 2];
                s1 += sstat[(w * BM + tid) * 2 + 1];
            }
            atomicAdd(&stats[(m0 + tid) * 2], s0);
            atomicAdd(&stats[(m0 + tid) * 2 + 1], s1);
        }
    }
}

// ---- final 64->3 conv (fused BN finalize + BN+ReLU on split input) ---------
__global__ __launch_bounds__(256) void finalconv_pm(
    const u16* __restrict__ y3, const float* __restrict__ statsIn,
    const float* __restrict__ gin, const float* __restrict__ bein,
    const float* __restrict__ wout, const float* __restrict__ bout,
    float* __restrict__ pts)
{
    __shared__ float swo[3][64];
    __shared__ float ssc[64], ssh[64];
    const int tid = threadIdx.x;
    if (tid < 192) swo[tid / 64][tid % 64] = wout[tid];
    if (tid < 64) {
        // fused c3 BN finalize (identical op order to old finalize_kernel)
        const float inv = 1.0f / (float)Nn;
        const float mean = statsIn[tid * 2] * inv;
        const float var = statsIn[tid * 2 + 1] * inv - mean * mean;
        const float sc = gin[tid] / sqrtf(var + EPSf);
        ssc[tid] = sc;
        ssh[tid] = fmaf(-mean, sc, bein[tid]);
    }
    __syncthreads();
    const int n = blockIdx.x * 256 + tid;
    const uint4* yph = (const uint4*)(y3 + (size_t)n * 128);
    float d0 = bout[0], d1 = bout[1], d2 = bout[2];
#pragma unroll
    for (int cc = 0; cc < 8; ++cc) {
        const uint4 H = yph[cc];
        const uint4 L = yph[8 + cc];
        const unsigned hu[4] = {H.x, H.y, H.z, H.w};
        const unsigned lu[4] = {L.x, L.y, L.z, L.w};
#pragma unroll
        for (int e = 0; e < 4; ++e) {
            const int c = cc * 8 + e * 2;
            const float v0 = fjoin((u16)(hu[e] & 0xffff), (u16)(lu[e] & 0xffff));
            const float v1 = fjoin((u16)(hu[e] >> 16), (u16)(lu[e] >> 16));
            const float a0 = fmaxf(fmaf(v0, ssc[c], ssh[c]), 0.f);
            const float a1 = fmaxf(fmaf(v1, ssc[c + 1], ssh[c + 1]), 0.f);
            d0 = fmaf(a0, swo[0][c], d0); d0 = fmaf(a1, swo[0][c + 1], d0);
            d1 = fmaf(a0, swo[1][c], d1); d1 = fmaf(a1, swo[1][c + 1], d1);
            d2 = fmaf(a0, swo[2][c], d2); d2 = fmaf(a1, swo[2][c + 1], d2);
        }
    }
    float4 p = {d0, d1, d2, d0 * d0 + d1 * d1 + d2 * d2};
    *(float4*)(pts + (size_t)n * 4) = p;
}

// ---- graph filtering: 16 threads/point, packed u32 keys --------------------
__global__ __launch_bounds__(512) void knn_kernel(const float* __restrict__ pts,
                                                  float* __restrict__ out) {
    __shared__ __align__(16) float4 sp[Mn];   // 32 KB -> 4 blocks/CU (wave cap)
    const int b = blockIdx.y;
    const int tid = threadIdx.x;
    const float4* pb = (const float4*)pts + (size_t)b * Mn;
    for (int i = tid; i < Mn; i += 512) sp[i] = pb[i];
    __syncthreads();
    const int lane = tid & 63;
    const int wv = tid >> 6;                    // 0..7
    const int seg = lane & 15;                  // segment 0..15 (128 cands each)
    const int ptl = (wv << 2) | (lane >> 4);    // point-local 0..31
    const int m = blockIdx.x * 32 + ptl;
    const float4 p = sp[m];
    // self-exclusion: only the owning segment can ever match (tt <= 127 < 128)
    const int cself = (seg == (m >> 7)) ? (m & 127) : 128;
    const int nb = seg << 7;
    unsigned bk[8];
#pragma unroll
    for (int k = 0; k < 8; ++k) bk[k] = 0xFFFFFFFFu;
    for (int t = 0; t < 128; ++t) {
        const int tt = (t + seg) & 127;         // stagger start by seg (bank tiling)
        const float4 q = sp[nb | tt];
        const float dot = fmaf(p.x, q.x, fmaf(p.y, q.y, p.z * q.z));
        float d = fmaf(-2.f, dot, q.w + p.w);   // true squared distance (+-ulp)
        d = fmaxf(d, 0.f);                      // keep uint-monotone (sign bit off)
        unsigned key = (__float_as_uint(d) & 0xFFFFFF80u) | (unsigned)tt;
        key = (tt == cself) ? 0xFFFFFFFFu : key;
        // branchless sorted insert, min/max only
        bk[7] = umin(bk[7], key);
#pragma unroll
        for (int k = 6; k >= 0; --k) {
            const unsigned lo = umin(bk[k], bk[k + 1]);
            bk[k + 1] = umax(bk[k], bk[k + 1]);
            bk[k] = lo;
        }
    }
    // keep originals for index recovery after the merge
    unsigned ok[8];
#pragma unroll
    for (int k = 0; k < 8; ++k) ok[k] = bk[k];
    // 4 bitonic merge rounds across the 16-lane group (partner = lane ^ r)
#pragma unroll
    for (int r = 1; r <= 8; r <<= 1) {
        unsigned od[8], md[8];
#pragma unroll
        for (int k = 0; k < 8; ++k) od[k] = (unsigned)__shfl_xor((int)bk[k], r);
#pragma unroll
        for (int k = 0; k < 8; ++k) md[k] = umin(bk[k], od[7 - k]);  // lowest-8 of union
#define CSU(a, c) { const unsigned lo_ = umin(md[a], md[c]); md[c] = umax(md[a], md[c]); md[a] = lo_; }
        CSU(0,4); CSU(1,5); CSU(2,6); CSU(3,7);
        CSU(0,2); CSU(1,3); CSU(4,6); CSU(5,7);
        CSU(0,1); CSU(2,3); CSU(4,5); CSU(6,7);
#undef CSU
#pragma unroll
        for (int k = 0; k < 8; ++k) bk[k] = md[k];
    }
    const unsigned TK = bk[7];                  // global 8th-smallest key
    // recovery: scan own 8 survivors vs TK; strict-less + equal-blend
    float slt[4] = {0.f, 0.f, 0.f, 0.f};        // x, y, z, count (key < TK)
    float seq[4] = {0.f, 0.f, 0.f, 0.f};        // x, y, z, count (key == TK)
#pragma unroll
    for (int k = 0; k < 8; ++k) {
        const unsigned key = ok[k];
        const float4 q = sp[nb | (int)(key & 127u)];
        const bool lt = key < TK;
        const bool eq = key == TK;
        slt[0] += lt ? q.x : 0.f; slt[1] += lt ? q.y : 0.f;
        slt[2] += lt ? q.z : 0.f; slt[3] += lt ? 1.f : 0.f;
        seq[0] += eq ? q.x : 0.f; seq[1] += eq ? q.y : 0.f;
        seq[2] += eq ? q.z : 0.f; seq[3] += eq ? 1.f : 0.f;
    }
#pragma unroll
    for (int r = 1; r <= 8; r <<= 1) {
#pragma unroll
        for (int k = 0; k < 4; ++k) {
            slt[k] += __shfl_xor(slt[k], r);
            seq[k] += __shfl_xor(seq[k], r);
        }
    }
    if (seg == 0) {
        const float scale = (8.f - slt[3]) / seq[3];   // seq[3] >= 1 guaranteed
        const float nx = fmaf(scale, seq[0], slt[0]);
        const float ny = fmaf(scale, seq[1], slt[1]);
        const float nz = fmaf(scale, seq[2], slt[2]);
        const float s8 = 0.125f;
        float* ob = out + (size_t)b * 3 * Mn;
        ob[m]          = 2.f * p.x - nx * s8;
        ob[Mn + m]     = 2.f * p.y - ny * s8;
        ob[2 * Mn + m] = 2.f * p.z - nz * s8;
    }
}

// ============================================================================
extern "C" void kernel_launch(void* const* d_in, const int* in_sizes, int n_in,
                              void* d_out, int out_size, void* d_ws, size_t ws_size,
                              hipStream_t stream)
{
    (void)in_sizes; (void)n_in; (void)out_size;
    const float* z     = (const float*)d_in[0];
    const float* s     = (const float*)d_in[1];
    const float* w_m1  = (const float*)d_in[2];
    const float* b_m1  = (const float*)d_in[3];
    const float* w_m2  = (const float*)d_in[4];
    const float* b_m2  = (const float*)d_in[5];
    const float* w_out = (const float*)d_in[6];
    const float* b_out = (const float*)d_in[7];
    const float* w_c[4]  = {(const float*)d_in[8],  (const float*)d_in[12], (const float*)d_in[16], (const float*)d_in[20]};
    const float* b_c[4]  = {(const float*)d_in[9],  (const float*)d_in[13], (const float*)d_in[17], (const float*)d_in[21]};
    const float* g_c[4]  = {(const float*)d_in[10], (const float*)d_in[14], (const float*)d_in[18], (const float*)d_in[22]};
    const float* be_c[4] = {(const float*)d_in[11], (const float*)d_in[15], (const float*)d_in[19], (const float*)d_in[23]};

    char* ws = (char*)d_ws;
    const size_t MB = 1024ull * 1024ull;
    float* outp = (float*)d_out;
    if (ws_size < 208 * MB) return;   // proven: harness provides >= 208 MiB

    // -------- split-fp16 MFMA path (peak 204 MiB) --------
    u16*   wbuf  = (u16*)ws;
    float* stats = (float*)(ws + 3 * MB);
    u16*   xs  = (u16*)(ws + 4 * MB);
    u16*   x1  = (u16*)(ws + 12 * MB);
    u16*   x2  = (u16*)(ws + 76 * MB);
    u16*   y0  = (u16*)(ws + 12 * MB);   // contiguous after both chunks (RAW)
    u16*   y0a = (u16*)(ws + 12 * MB);   // rows [0, 32K)
    u16*   y0b = (u16*)(ws + 76 * MB);   // rows [32K, 64K)
    u16*   y1  = (u16*)(ws + 140 * MB);  // RAW c1 output
    u16*   y2  = (u16*)(ws + 12 * MB);   // RAW c2 output
    u16*   y3  = (u16*)(ws + 76 * MB);   // RAW c3 output
    float* pts = (float*)(ws + 4 * MB);

    prep_kernel<<<2497, 256, 0, stream>>>(w_m1, w_m2, w_c[0], w_c[1], w_c[2], w_c[3], s, wbuf, xs, stats);
    // m1: [N][32] -> [N][256]  (128x128, 256 thr; 1024 blocks)
    mfma_gemm<2, 2, 0, 2, 0, 32, 256><<<1024, 256, 0, stream>>>(wbuf, xs, x1, b_m1, nullptr, nullptr, nullptr, nullptr, nullptr, 256);
    // m2: [N][256] -> [N][512] (256x128, 512 thr; 1024 blocks)
    mfma_gemm<4, 2, 1, 2, 0, 256, 512><<<1024, 512, 0, stream>>>(wbuf + 16384, x1, x2, b_m2, z, nullptr, nullptr, nullptr, nullptr, 512);
    // c0 a/b: rows halves (256x128; 512 blocks each) -> RAW y0 + stats
    // (NOT mergeable: y0b overwrites x2 rows [0,32K) which c0a reads -> sequential)
    mfma_gemm<4, 2, 2, 2, 0, 512, 512><<<512, 512, 0, stream>>>(wbuf + 278528, x2, y0a, b_c[0], nullptr, nullptr, nullptr, nullptr, stats + 0, 512);
    mfma_gemm<4, 2, 2, 2, 0, 512, 512><<<512, 512, 0, stream>>>(wbuf + 278528, x2 + (size_t)Hn * 1024, y0b, b_c[0], nullptr, nullptr, nullptr, nullptr, stats + 0, 512);
    // c1: BN0 finalize fused (256x128, MY=1 -> 512 blocks); RAW y1 + stats
    mfma_gemm<4, 2, 2, 1, 1, 512, 512><<<512, 512, 0, stream>>>(wbuf + 802816, y0, y1, b_c[1], nullptr, stats + 0, g_c[0], be_c[0], stats + 1024, 256);
    // c2: BN1 finalize fused (128x256, 512 thr, MY=1 -> 256 blocks); RAW y2 + stats
    mfma_gemm<2, 4, 2, 1, 1, 256, 512><<<256, 512, 0, stream>>>(wbuf + 1064960, y1, y2, b_c[2], nullptr, stats + 1024, g_c[1], be_c[1], stats + 2048, 128);
    // c3: BN2 finalize fused (64x256, 256 thr = 1x4 wave grid; 256 blocks); RAW y3 + stats
    mfma_gemm<1, 4, 2, 1, 1, 128, 256><<<256, 256, 0, stream>>>(wbuf + 1130496, y2, y3, b_c[3], nullptr, stats + 2048, g_c[2], be_c[2], stats + 3072, 64);
    // finalconv: BN3 finalize fused from stats+3072
    finalconv_pm<<<Nn / 256, 256, 0, stream>>>(y3, stats + 3072, g_c[3], be_c[3], w_out, b_out, pts);
    knn_kernel<<<dim3(Mn / 32, Bn), 512, 0, stream>>>(pts, outp);
}